// Round 1
// baseline (1016.593 us; speedup 1.0000x reference)
//
#include <hip/hip_runtime.h>

// Problem constants
#define B_ 16
#define N_ 8192
#define D_ 512
#define M_ 1024
#define BT 32            // tokens per workgroup
#define PADROW 1032      // bf16 elems per LDS row (pad 8 -> stride 2064 B, uniform banks)
#define SCALE 0.04419417382415922f  // 1/sqrt(512)

typedef __attribute__((ext_vector_type(8))) short short8;
typedef __attribute__((ext_vector_type(4))) float f32x4;

__device__ __forceinline__ unsigned short f2bf(float f) {
  unsigned int u = __float_as_uint(f);
  u += 0x7FFFu + ((u >> 16) & 1u);   // round-to-nearest-even
  return (unsigned short)(u >> 16);
}
__device__ __forceinline__ float bf2f(unsigned short h) {
  return __uint_as_float(((unsigned int)h) << 16);
}

#define MFMA(a, b, c) __builtin_amdgcn_mfma_f32_16x16x32_bf16((a), (b), (c), 0, 0, 0)

// Convert mem fp32 [D][M] -> bf16 [D][M] (for GEMM2 B) and bf16 [M][D] (for GEMM1 B)
__global__ void prep_mem_kernel(const float* __restrict__ mem,
                                unsigned short* __restrict__ memb,
                                unsigned short* __restrict__ memTb) {
  int idx = blockIdx.x * 256 + threadIdx.x;   // 0 .. D*M-1
  float v = mem[idx];
  unsigned short b = f2bf(v);
  memb[idx] = b;
  int d = idx >> 10;          // M_ = 1024
  int m = idx & (M_ - 1);
  memTb[m * D_ + d] = b;
}

__global__ __launch_bounds__(256, 2) void fused_kernel(
    const float* __restrict__ x, const unsigned short* __restrict__ memb,
    const unsigned short* __restrict__ memTb, float* __restrict__ out) {
  __shared__ unsigned short sP[BT * PADROW];   // 66 KB: X staging, then S/P
  __shared__ float sInv[BT];

  const int tid = threadIdx.x;
  const int wave = tid >> 6;
  const int lane = tid & 63;
  const int r = lane & 15;     // fragment row/col index
  const int g = lane >> 4;     // fragment k-group
  const long t0 = (long)blockIdx.x * BT;   // first token of this block

  // ---- Stage X (pre-scaled by 1/sqrt(D)) as bf16 into sP[row][0..511] ----
  {
    const int row = tid >> 3;            // 0..31
    const int c0 = (tid & 7) * 64;       // 64 cols per thread
    const float* xp = x + (t0 + row) * (long)D_ + c0;
    unsigned short* dst = &sP[row * PADROW + c0];
#pragma unroll
    for (int j = 0; j < 64; j += 8) {
      f32x4 v0 = *(const f32x4*)(xp + j);
      f32x4 v1 = *(const f32x4*)(xp + j + 4);
      short8 o;
      o[0] = (short)f2bf(v0[0] * SCALE);
      o[1] = (short)f2bf(v0[1] * SCALE);
      o[2] = (short)f2bf(v0[2] * SCALE);
      o[3] = (short)f2bf(v0[3] * SCALE);
      o[4] = (short)f2bf(v1[0] * SCALE);
      o[5] = (short)f2bf(v1[1] * SCALE);
      o[6] = (short)f2bf(v1[2] * SCALE);
      o[7] = (short)f2bf(v1[3] * SCALE);
      *(short8*)(dst + j) = o;
    }
  }
  __syncthreads();

  // ---- Load A fragments (X) for both 16-row blocks, all K=512 (128 VGPR) ----
  short8 afr0[16], afr1[16];
#pragma unroll
  for (int k0 = 0; k0 < 16; k0++) {
    afr0[k0] = *(const short8*)(&sP[r * PADROW + k0 * 32 + g * 8]);
    afr1[k0] = *(const short8*)(&sP[(16 + r) * PADROW + k0 * 32 + g * 8]);
  }
  __syncthreads();   // X region in sP will be overwritten by S

  // ---- GEMM1: S[32 rows][m-quarter of this wave], B-frags streamed from L2 ----
  {
    const int mq = wave * 256;
    for (int m0 = 0; m0 < 16; m0++) {
      const int mg = mq + m0 * 16;
      f32x4 acc0 = {0.f, 0.f, 0.f, 0.f};
      f32x4 acc1 = {0.f, 0.f, 0.f, 0.f};
      // B-frag: lane holds memT[mg + r][k0*32 + g*8 + j], contiguous 16 B
      const unsigned short* bp = memTb + (mg + r) * D_ + g * 8;
#pragma unroll
      for (int k0 = 0; k0 < 16; k0++) {
        short8 b = *(const short8*)(bp + k0 * 32);
        acc0 = MFMA(afr0[k0], b, acc0);
        acc1 = MFMA(afr1[k0], b, acc1);
      }
      // C-frag: row = g*4 + i, col = mg + r  -> write S as bf16
#pragma unroll
      for (int i = 0; i < 4; i++) {
        sP[(g * 4 + i) * PADROW + mg + r] = f2bf(acc0[i]);
        sP[(16 + g * 4 + i) * PADROW + mg + r] = f2bf(acc1[i]);
      }
    }
  }
  __syncthreads();

  // ---- Softmax over m (1024) per token row; 8 threads per row ----
  {
    const int row = tid >> 3;
    unsigned short* p = &sP[row * PADROW + (tid & 7) * 128];
    float mx = -3.0e38f;
    for (int j = 0; j < 128; j += 8) {
      short8 v = *(const short8*)(p + j);
#pragma unroll
      for (int e = 0; e < 8; e++) mx = fmaxf(mx, bf2f((unsigned short)v[e]));
    }
    mx = fmaxf(mx, __shfl_xor(mx, 1));
    mx = fmaxf(mx, __shfl_xor(mx, 2));
    mx = fmaxf(mx, __shfl_xor(mx, 4));
    float sum = 0.f;
    for (int j = 0; j < 128; j += 8) {
      short8 v = *(const short8*)(p + j);
      short8 o;
#pragma unroll
      for (int e = 0; e < 8; e++) {
        float pe = __expf(bf2f((unsigned short)v[e]) - mx);
        unsigned short pb = f2bf(pe);
        o[e] = (short)pb;
        sum += bf2f(pb);   // sum the rounded values GEMM2 will actually use
      }
      *(short8*)(p + j) = o;
    }
    sum += __shfl_xor(sum, 1);
    sum += __shfl_xor(sum, 2);
    sum += __shfl_xor(sum, 4);
    if ((tid & 7) == 0) sInv[row] = 1.0f / sum;
  }
  __syncthreads();

  // ---- GEMM2: out[32 rows][d-quarter of this wave] = P * memT, scaled by 1/sum ----
  {
    const int dq = wave * 128;
    f32x4 acc0[8], acc1[8];
#pragma unroll
    for (int i = 0; i < 8; i++) {
      acc0[i] = (f32x4){0.f, 0.f, 0.f, 0.f};
      acc1[i] = (f32x4){0.f, 0.f, 0.f, 0.f};
    }
    for (int k0 = 0; k0 < 32; k0++) {
      // A-frag: P[row r][k0*32 + g*8 + j] from LDS
      short8 a0 = *(const short8*)(&sP[r * PADROW + k0 * 32 + g * 8]);
      short8 a1 = *(const short8*)(&sP[(16 + r) * PADROW + k0 * 32 + g * 8]);
      // B-frag: memT[k][d] = memb[d * M + k]; lane holds d = dq + d0*16 + r
      const unsigned short* bp = memb + (dq + r) * M_ + k0 * 32 + g * 8;
#pragma unroll
      for (int d0 = 0; d0 < 8; d0++) {
        short8 b = *(const short8*)(bp + d0 * 16 * M_);
        acc0[d0] = MFMA(a0, b, acc0[d0]);
        acc1[d0] = MFMA(a1, b, acc1[d0]);
      }
    }
    float inv0[4], inv1[4];
#pragma unroll
    for (int i = 0; i < 4; i++) {
      inv0[i] = sInv[g * 4 + i];
      inv1[i] = sInv[16 + g * 4 + i];
    }
#pragma unroll
    for (int d0 = 0; d0 < 8; d0++) {
#pragma unroll
      for (int i = 0; i < 4; i++) {
        out[(t0 + g * 4 + i) * (long)D_ + dq + d0 * 16 + r] = acc0[d0][i] * inv0[i];
        out[(t0 + 16 + g * 4 + i) * (long)D_ + dq + d0 * 16 + r] = acc1[d0][i] * inv1[i];
      }
    }
  }
}

extern "C" void kernel_launch(void* const* d_in, const int* in_sizes, int n_in,
                              void* d_out, int out_size, void* d_ws, size_t ws_size,
                              hipStream_t stream) {
  const float* x = (const float*)d_in[0];
  const float* mem = (const float*)d_in[1];
  float* out = (float*)d_out;
  unsigned short* memb = (unsigned short*)d_ws;            // [D][M] bf16, 1 MB
  unsigned short* memTb = memb + (size_t)D_ * M_;          // [M][D] bf16, 1 MB

  hipLaunchKernelGGL(prep_mem_kernel, dim3((D_ * M_) / 256), dim3(256), 0, stream,
                     mem, memb, memTb);
  hipLaunchKernelGGL(fused_kernel, dim3((B_ * N_) / BT), dim3(256), 0, stream,
                     x, memb, memTb, out);
}

// Round 2
// 596.122 us; speedup vs baseline: 1.7053x; 1.7053x over previous
//
#include <hip/hip_runtime.h>

#define B_ 16
#define N_ 8192
#define D_ 512
#define M_ 1024
#define BT 64
#define XPAD 520    // X row stride (bf16 elems): 1040 B
#define PPAD 1032   // P row stride (bf16 elems): 2064 B
#define SCALE 0.04419417382415922f  // 1/sqrt(512)

typedef __attribute__((ext_vector_type(8))) short short8;
typedef __attribute__((ext_vector_type(4))) float f32x4;

__device__ __forceinline__ unsigned short f2bf(float f) {
  unsigned int u = __float_as_uint(f);
  u += 0x7FFFu + ((u >> 16) & 1u);   // RNE
  return (unsigned short)(u >> 16);
}
__device__ __forceinline__ float bf2f(unsigned short h) {
  return __uint_as_float(((unsigned int)h) << 16);
}

#define MFMA(a, b, c) __builtin_amdgcn_mfma_f32_16x16x32_bf16((a), (b), (c), 0, 0, 0)

// memTb[m][d] = bf16(mem[d][m])           (GEMM1 B operand, natural m order)
// membP[d][c'] = bf16(mem[d][m(c')])      (GEMM2 B operand, permuted m order)
// permutation within each 128-block: c' = r*8 + m0  <->  m = m0*16 + r
__global__ void prep_mem_kernel(const float* __restrict__ mem,
                                unsigned short* __restrict__ memTb,
                                unsigned short* __restrict__ membP) {
  int idx = blockIdx.x * 256 + threadIdx.x;   // 0..D*M-1
  float v = mem[idx];
  unsigned short b = f2bf(v);
  int d = idx >> 10;
  int m = idx & (M_ - 1);
  memTb[m * D_ + d] = b;
  int c = (m & ~127) | ((m & 15) << 3) | ((m >> 4) & 7);
  membP[d * M_ + c] = b;
}

__global__ __launch_bounds__(512, 2) void fused_kernel(
    const float* __restrict__ x, const unsigned short* __restrict__ memTb,
    const unsigned short* __restrict__ membP, float* __restrict__ out) {
  __shared__ unsigned short sP[BT * PPAD];   // 129 KB: X (XPAD stride) then P (PPAD stride)
  __shared__ float smax[8][BT];
  __shared__ float ssum[8][BT];
  __shared__ float gmax[BT];
  __shared__ float sInv[BT];

  const int tid = threadIdx.x;
  const int w = tid >> 6;       // wave 0..7
  const int lane = tid & 63;
  const int r = lane & 15;
  const int g = lane >> 4;
  const long t0 = (long)blockIdx.x * BT;

  // ---- Phase 0: stage X (scaled, bf16) into sP, interleaved 16B chunks ----
  {
    const int row = tid >> 3;          // 0..63
    const int cb = (tid & 7) * 8;      // interleave: col = cb + j*64
    const float* xp = x + (t0 + row) * (long)D_;
    unsigned short* dst = &sP[row * XPAD];
#pragma unroll
    for (int j = 0; j < 8; j++) {
      const int c = cb + j * 64;
      f32x4 v0 = *(const f32x4*)(xp + c);
      f32x4 v1 = *(const f32x4*)(xp + c + 4);
      short8 o;
      o[0] = (short)f2bf(v0[0] * SCALE);
      o[1] = (short)f2bf(v0[1] * SCALE);
      o[2] = (short)f2bf(v0[2] * SCALE);
      o[3] = (short)f2bf(v0[3] * SCALE);
      o[4] = (short)f2bf(v1[0] * SCALE);
      o[5] = (short)f2bf(v1[1] * SCALE);
      o[6] = (short)f2bf(v1[2] * SCALE);
      o[7] = (short)f2bf(v1[3] * SCALE);
      *(short8*)(dst + c) = o;
    }
  }
  __syncthreads();

  // ---- Phase 1: GEMM1. S[64 tok x 128 m] per wave, in registers ----
  f32x4 acc[8][4];   // [m0][tb]; token = tb*16+g*4+i, m = w*128 + m0*16 + r
#pragma unroll
  for (int m0 = 0; m0 < 8; m0++)
#pragma unroll
    for (int tb = 0; tb < 4; tb++) acc[m0][tb] = (f32x4){0.f, 0.f, 0.f, 0.f};
  {
    const unsigned short* bb = memTb + (long)(w * 128 + r) * D_ + g * 8;
#pragma unroll 2
    for (int k0 = 0; k0 < 16; k0++) {
      short8 a0 = *(const short8*)(&sP[(r)*XPAD + k0 * 32 + g * 8]);
      short8 a1 = *(const short8*)(&sP[(16 + r) * XPAD + k0 * 32 + g * 8]);
      short8 a2 = *(const short8*)(&sP[(32 + r) * XPAD + k0 * 32 + g * 8]);
      short8 a3 = *(const short8*)(&sP[(48 + r) * XPAD + k0 * 32 + g * 8]);
#pragma unroll
      for (int m0 = 0; m0 < 8; m0++) {
        short8 b = *(const short8*)(bb + (long)m0 * 16 * D_ + k0 * 32);
        acc[m0][0] = MFMA(a0, b, acc[m0][0]);
        acc[m0][1] = MFMA(a1, b, acc[m0][1]);
        acc[m0][2] = MFMA(a2, b, acc[m0][2]);
        acc[m0][3] = MFMA(a3, b, acc[m0][3]);
      }
    }
  }

  // ---- Phase 2: per-wave partial row max -> cross-wave max ----
  float mx[4][4];
#pragma unroll
  for (int tb = 0; tb < 4; tb++)
#pragma unroll
    for (int i = 0; i < 4; i++) {
      float m = acc[0][tb][i];
#pragma unroll
      for (int m0 = 1; m0 < 8; m0++) m = fmaxf(m, acc[m0][tb][i]);
      mx[tb][i] = m;
    }
#pragma unroll
  for (int s = 1; s <= 8; s <<= 1)
#pragma unroll
    for (int tb = 0; tb < 4; tb++)
#pragma unroll
      for (int i = 0; i < 4; i++)
        mx[tb][i] = fmaxf(mx[tb][i], __shfl_xor(mx[tb][i], s));
  if (r == 0) {
#pragma unroll
    for (int tb = 0; tb < 4; tb++)
#pragma unroll
      for (int i = 0; i < 4; i++) smax[w][tb * 16 + g * 4 + i] = mx[tb][i];
  }
  __syncthreads();
  if (tid < BT) {
    float m = smax[0][tid];
#pragma unroll
    for (int ww = 1; ww < 8; ww++) m = fmaxf(m, smax[ww][tid]);
    gmax[tid] = m;
  }
  __syncthreads();

  // ---- Phase 3: P = exp(S-gmax) -> bf16 -> LDS (permuted cols, b128 writes) ----
  {
    const int wm = w * 128;
    float sm[4][4];
#pragma unroll
    for (int tb = 0; tb < 4; tb++) {
#pragma unroll
      for (int i = 0; i < 4; i++) {
        const int tok = tb * 16 + g * 4 + i;
        const float gm = gmax[tok];
        short8 o;
        float s = 0.f;
#pragma unroll
        for (int m0 = 0; m0 < 8; m0++) {
          float p = __expf(acc[m0][tb][i] - gm);
          unsigned short pb = f2bf(p);
          o[m0] = (short)pb;
          s += bf2f(pb);   // sum the rounded values GEMM2 will use
        }
        sm[tb][i] = s;
        *(short8*)(&sP[tok * PPAD + wm + r * 8]) = o;
      }
    }
#pragma unroll
    for (int s = 1; s <= 8; s <<= 1)
#pragma unroll
      for (int tb = 0; tb < 4; tb++)
#pragma unroll
        for (int i = 0; i < 4; i++) sm[tb][i] += __shfl_xor(sm[tb][i], s);
    if (r == 0) {
#pragma unroll
      for (int tb = 0; tb < 4; tb++)
#pragma unroll
        for (int i = 0; i < 4; i++) ssum[w][tb * 16 + g * 4 + i] = sm[tb][i];
    }
  }
  __syncthreads();
  if (tid < BT) {
    float s = ssum[0][tid];
#pragma unroll
    for (int ww = 1; ww < 8; ww++) s += ssum[ww][tid];
    sInv[tid] = 1.0f / s;
  }
  __syncthreads();

  // ---- Phase 4: GEMM2. O[64 tok x 64 d] per wave ----
  f32x4 oacc[4][4];  // [tb][d0]; token = tb*16+g*4+i, d = w*64 + d0*16 + r
#pragma unroll
  for (int tb = 0; tb < 4; tb++)
#pragma unroll
    for (int d0 = 0; d0 < 4; d0++) oacc[tb][d0] = (f32x4){0.f, 0.f, 0.f, 0.f};
  {
    const unsigned short* bb = membP + (long)(w * 64 + r) * M_ + g * 8;
#pragma unroll 2
    for (int k0 = 0; k0 < 32; k0++) {
      short8 a0 = *(const short8*)(&sP[(r)*PPAD + k0 * 32 + g * 8]);
      short8 a1 = *(const short8*)(&sP[(16 + r) * PPAD + k0 * 32 + g * 8]);
      short8 a2 = *(const short8*)(&sP[(32 + r) * PPAD + k0 * 32 + g * 8]);
      short8 a3 = *(const short8*)(&sP[(48 + r) * PPAD + k0 * 32 + g * 8]);
      short8 b0 = *(const short8*)(bb + 0L * 16 * M_ + k0 * 32);
      short8 b1 = *(const short8*)(bb + 1L * 16 * M_ + k0 * 32);
      short8 b2 = *(const short8*)(bb + 2L * 16 * M_ + k0 * 32);
      short8 b3 = *(const short8*)(bb + 3L * 16 * M_ + k0 * 32);
      oacc[0][0] = MFMA(a0, b0, oacc[0][0]);
      oacc[0][1] = MFMA(a0, b1, oacc[0][1]);
      oacc[0][2] = MFMA(a0, b2, oacc[0][2]);
      oacc[0][3] = MFMA(a0, b3, oacc[0][3]);
      oacc[1][0] = MFMA(a1, b0, oacc[1][0]);
      oacc[1][1] = MFMA(a1, b1, oacc[1][1]);
      oacc[1][2] = MFMA(a1, b2, oacc[1][2]);
      oacc[1][3] = MFMA(a1, b3, oacc[1][3]);
      oacc[2][0] = MFMA(a2, b0, oacc[2][0]);
      oacc[2][1] = MFMA(a2, b1, oacc[2][1]);
      oacc[2][2] = MFMA(a2, b2, oacc[2][2]);
      oacc[2][3] = MFMA(a2, b3, oacc[2][3]);
      oacc[3][0] = MFMA(a3, b0, oacc[3][0]);
      oacc[3][1] = MFMA(a3, b1, oacc[3][1]);
      oacc[3][2] = MFMA(a3, b2, oacc[3][2]);
      oacc[3][3] = MFMA(a3, b3, oacc[3][3]);
    }
  }

  // ---- Epilogue: scale by 1/sum, store ----
  {
    const int dq = w * 64;
#pragma unroll
    for (int tb = 0; tb < 4; tb++) {
#pragma unroll
      for (int i = 0; i < 4; i++) {
        const int tok = tb * 16 + g * 4 + i;
        const float inv = sInv[tok];
        float* op = out + (t0 + tok) * (long)D_ + dq + r;
#pragma unroll
        for (int d0 = 0; d0 < 4; d0++) op[d0 * 16] = oacc[tb][d0][i] * inv;
      }
    }
  }
}

extern "C" void kernel_launch(void* const* d_in, const int* in_sizes, int n_in,
                              void* d_out, int out_size, void* d_ws, size_t ws_size,
                              hipStream_t stream) {
  const float* x = (const float*)d_in[0];
  const float* mem = (const float*)d_in[1];
  float* out = (float*)d_out;
  unsigned short* memTb = (unsigned short*)d_ws;           // [M][D] bf16, 1 MB
  unsigned short* membP = memTb + (size_t)D_ * M_;         // [D][M'] bf16, 1 MB

  hipLaunchKernelGGL(prep_mem_kernel, dim3((D_ * M_) / 256), dim3(256), 0, stream,
                     mem, memTb, membP);
  hipLaunchKernelGGL(fused_kernel, dim3((B_ * N_) / BT), dim3(512), 0, stream,
                     x, memTb, membP, out);
}